// Round 10
// baseline (208.288 us; speedup 1.0000x reference)
//
#include <hip/hip_runtime.h>
#include <hip/hip_bf16.h>

#define B_   8
#define C_   256
#define CQ_  32
#define N_   4096
#define OC_  320   // stacked output channels: q 0..31 | k 32..63 | v 64..319

typedef __bf16 bf16;
typedef __attribute__((ext_vector_type(8))) __bf16 bf16x8;
typedef __attribute__((ext_vector_type(4))) __bf16 bf16x4;
typedef __attribute__((ext_vector_type(4))) float f32x4;

#define LOG2E 1.4426950408889634f

// ws layout (bf16 element offsets):
//   qT [B][N][CQ] | kT [B][N][CQ] | vb [B][C][N] | Wb [320][256] | xT [B][N][C]
//   then fp32 bias[320] at byte offset BIAS_BYTE.
#define QT_OFF ((size_t)0)
#define KT_OFF ((size_t)B_*N_*CQ_)
#define VB_OFF ((size_t)2*B_*N_*CQ_)
#define WB_OFF (VB_OFF + (size_t)B_*C_*N_)
#define XT_OFF (WB_OFF + (size_t)OC_*C_)
#define WS_END_BF16 (XT_OFF + (size_t)B_*N_*C_)
#define BIAS_BYTE (WS_END_BF16*2)
#define WS_BYTES (BIAS_BYTE + OC_*4)

// exp2 via builtin (compiler-visible TRANS op; hazards handled).
__device__ inline float exp2_hw(float x) {
  return __builtin_amdgcn_exp2f(x);
}

// P-row swizzle: rows are 256B; XOR bits 4-6 spread the 8 16B slots per 128B
// half, bit 7 splits m vs m+8 into different halves (m/m+8 bank aliasing was
// the measured conflict source). Lane-constant per kernel (m = lm + 16*ms
// => m&7 and (m>>3)&1 depend only on lm).
__device__ inline int swz(int m) {
  return ((m & 7) << 4) ^ (((m >> 3) & 1) << 7);
}

// ---------------------------------------------------------------------------
// prep_w: stack Wq|Wk|Wv -> bf16 Wb[320][256], biases -> fp32[320].
// ---------------------------------------------------------------------------
__global__ __launch_bounds__(256) void prep_w(
    const float* __restrict__ Wq, const float* __restrict__ bq,
    const float* __restrict__ Wk, const float* __restrict__ bk,
    const float* __restrict__ Wv, const float* __restrict__ bv,
    bf16* __restrict__ ws)
{
  const int idx = blockIdx.x*256 + threadIdx.x;      // 0..81919
  const int o = idx >> 8, c = idx & 255;
  const float v = (o < 32) ? Wq[o*C_ + c]
                : (o < 64) ? Wk[(o-32)*C_ + c]
                           : Wv[(o-64)*C_ + c];
  ws[WB_OFF + idx] = (bf16)v;
  if (idx < OC_) {
    const float bb = (idx < 32) ? bq[idx] : (idx < 64) ? bk[idx-32] : bv[idx-64];
    ((float*)((char*)ws + BIAS_BYTE))[idx] = bb;
  }
}

// ---------------------------------------------------------------------------
// prep_x: x fp32 [B][C][N] -> bf16 xT [B][N][C] (B-frag layout, contiguous c).
// ---------------------------------------------------------------------------
__global__ __launch_bounds__(256) void prep_x(
    const float* __restrict__ x, bf16* __restrict__ ws)
{
  const int b  = blockIdx.z;
  const int n  = blockIdx.x*64 + (threadIdx.x & 63);
  const int c0 = blockIdx.y*32 + (threadIdx.x >> 6)*8;
  const float* xp = x + ((size_t)b*C_ + c0)*N_ + n;
  bf16x8 pk;
  #pragma unroll
  for (int j = 0; j < 8; ++j) pk[j] = (bf16)xp[(size_t)j*N_];
  *(bf16x8*)(ws + XT_OFF + ((size_t)b*N_ + n)*C_ + c0) = pk;
}

// ---------------------------------------------------------------------------
// qkv_mfma: D[o][n] = sum_c Wb[o][c] xT[n][c] + bias[o]. Per block: 320 o x
// 64 n. 4 waves; wave w owns 5 o-tiles. K=256 in 8 MFMA steps, no LDS.
// q outputs pre-scaled by LOG2E so attention uses raw 2^x.
// ---------------------------------------------------------------------------
__global__ __launch_bounds__(256) void qkv_mfma(
    const bf16* __restrict__ wsc, bf16* __restrict__ ws)
{
  const int b   = blockIdx.y;
  const int n0  = blockIdx.x * 64;
  const int tid = threadIdx.x, lane = tid & 63;
  const int w   = __builtin_amdgcn_readfirstlane(tid >> 6);
  const int lm  = lane & 15, g = lane >> 4;
  const int obase = w*80;

  const bf16*  Wb   = wsc + WB_OFF;
  const bf16*  xT   = wsc + XT_OFF + (size_t)b*N_*C_;
  const float* bias = (const float*)((const char*)wsc + BIAS_BYTE);

  f32x4 acc[5][4];
  #pragma unroll
  for (int ot = 0; ot < 5; ++ot)
    #pragma unroll
    for (int nt = 0; nt < 4; ++nt)
      acc[ot][nt] = (f32x4){0.f, 0.f, 0.f, 0.f};

  for (int kk = 0; kk < 8; ++kk) {
    bf16x8 wa[5], xf[4];
    #pragma unroll
    for (int ot = 0; ot < 5; ++ot)
      wa[ot] = *(const bf16x8*)(Wb + (size_t)(obase + ot*16 + lm)*C_ + kk*32 + g*8);
    #pragma unroll
    for (int nt = 0; nt < 4; ++nt)
      xf[nt] = *(const bf16x8*)(xT + (size_t)(n0 + nt*16 + lm)*C_ + kk*32 + g*8);
    #pragma unroll
    for (int ot = 0; ot < 5; ++ot)
      #pragma unroll
      for (int nt = 0; nt < 4; ++nt)
        acc[ot][nt] = __builtin_amdgcn_mfma_f32_16x16x32_bf16(
                        wa[ot], xf[nt], acc[ot][nt], 0, 0, 0);
  }

  float bv4[5][4];
  #pragma unroll
  for (int ot = 0; ot < 5; ++ot)
    #pragma unroll
    for (int r = 0; r < 4; ++r)
      bv4[ot][r] = bias[obase + ot*16 + g*4 + r];

  bf16* qT = ws + QT_OFF + (size_t)b*N_*CQ_;
  bf16* kT = ws + KT_OFF + (size_t)b*N_*CQ_;
  bf16* vb = ws + VB_OFF + (size_t)b*C_*N_;

  #pragma unroll
  for (int ot = 0; ot < 5; ++ot) {
    const int O = obase + ot*16;
    #pragma unroll
    for (int nt = 0; nt < 4; ++nt) {
      const int n = n0 + nt*16 + lm;
      if (O < 32) {
        bf16x4 pk;   // q: fold log2(e)
        #pragma unroll
        for (int r = 0; r < 4; ++r)
          pk[r] = (bf16)((acc[ot][nt][r] + bv4[ot][r]) * LOG2E);
        *(bf16x4*)(qT + (size_t)n*CQ_ + O + g*4) = pk;
      } else if (O < 64) {
        bf16x4 pk;
        #pragma unroll
        for (int r = 0; r < 4; ++r) pk[r] = (bf16)(acc[ot][nt][r] + bv4[ot][r]);
        *(bf16x4*)(kT + (size_t)n*CQ_ + (O - 32) + g*4) = pk;
      } else {
        #pragma unroll
        for (int r = 0; r < 4; ++r)
          vb[(size_t)(O - 64 + g*4 + r)*N_ + n] = (bf16)(acc[ot][nt][r] + bv4[ot][r]);
      }
    }
  }
}

// ---------------------------------------------------------------------------
// attn_kernel v6: v2 skeleton + c-split x2 + fixed P swizzle.
// grid 1024 = (b 8) x (m-tile 64) x (c-half 2). 8 waves / 512 threads.
// launch_bounds(512,6) -> 3 blocks/CU (24 waves, 75% occ), VGPR budget 85
// (est ~72, no spill). Per block: n-tile 128, 32 phases.
// Wave w: QK^T slab rows n0+w*16 (4 MFMAs) -> exp2 -> swizzled LDS P
// [64][256B] dbuf -> __syncthreads -> PV over c-range c0b+w*16 (16 MFMAs).
// Both c-half blocks duplicate QK^T/exp (11% extra MFMA) but read only their
// half of v; outputs are disjoint so no cross-block combining.
// ---------------------------------------------------------------------------
__global__ __launch_bounds__(512, 6) void attn_kernel(
    const bf16* __restrict__ ws, const float* __restrict__ x,
    const float* __restrict__ gamma, float* __restrict__ out)
{
  const int bid  = blockIdx.x;
  const int b    = bid & 7;
  const int m0   = ((bid >> 3) & 63) << 6;
  const int c0b  = (bid >> 9) << 7;       // c-half base: 0 or 128
  const int tid  = threadIdx.x;
  const int lane = tid & 63;
  const int w    = __builtin_amdgcn_readfirstlane(tid >> 6);   // 0..7
  const int lm   = lane & 15;
  const int g    = lane >> 4;

  const bf16* qT = ws + QT_OFF + (size_t)b*N_*CQ_;
  const bf16* kT = ws + KT_OFF + (size_t)b*N_*CQ_;
  const bf16* vb = ws + VB_OFF + (size_t)b*C_*N_;

  __shared__ __align__(16) char Pb[2][64*256]; // [buf][m][256B swizzled row]
  __shared__ float red[8][64];
  __shared__ float dsh[64];

  // k B-frags for the block's 64 columns (constant over loop)
  bf16x8 kb[4];
  #pragma unroll
  for (int ms = 0; ms < 4; ++ms)
    kb[ms] = *(const bf16x8*)(kT + (size_t)(m0 + ms*16 + lm)*CQ_ + g*8);

  f32x4 acc[4];                    // [m-subtile]; c-range is 16 rows (1 tile)
  #pragma unroll
  for (int ms = 0; ms < 4; ++ms)
    acc[ms] = (f32x4){0.f, 0.f, 0.f, 0.f};
  float colsum[4] = {0.f, 0.f, 0.f, 0.f};

  const int cb  = c0b + w*16;      // this wave's PV c-range
  const int swb = w*32 + g*8;      // P-write byte base (2*n_local), pre-XOR
  const f32x4 zero4 = (f32x4){0.f, 0.f, 0.f, 0.f};

  // per-wave source pointers
  const bf16* qp  = qT + (size_t)(w*16 + lm)*CQ_ + g*8;   // + n*CQ_
  const bf16* vp  = vb + (size_t)(cb + lm)*N_ + g*8;      // + n

  for (int t = 0; t < 32; ++t) {
    const size_t n0 = (size_t)t * 128;
    char* pbuf = Pb[t & 1];

    // ---- issue q + kc0,1 v-frags (consumed after QKT / early PV) ----
    bf16x8 qf = *(const bf16x8*)(qp + n0*CQ_);
    bf16x8 vfA[2];
    #pragma unroll
    for (int kc = 0; kc < 2; ++kc)
      vfA[kc] = *(const bf16x8*)(vp + n0 + kc*32);

    // ---- QK^T: S slab [16 n][64 m] ----
    f32x4 s[4];
    #pragma unroll
    for (int ms = 0; ms < 4; ++ms)
      s[ms] = __builtin_amdgcn_mfma_f32_16x16x32_bf16(qf, kb[ms], zero4, 0, 0, 0);

    // ---- exp2 / colsum / pack / swizzled P write ----
    #pragma unroll
    for (int ms = 0; ms < 4; ++ms) {
      float p0 = exp2_hw(s[ms][0]);
      float p1 = exp2_hw(s[ms][1]);
      float p2 = exp2_hw(s[ms][2]);
      float p3 = exp2_hw(s[ms][3]);
      colsum[ms] += (p0 + p1) + (p2 + p3);
      bf16x4 pk;
      pk[0] = (bf16)p0; pk[1] = (bf16)p1; pk[2] = (bf16)p2; pk[3] = (bf16)p3;
      const int m = lm + 16*ms;
      *(bf16x4*)(pbuf + m*256 + (swb ^ swz(m))) = pk;
    }
    __syncthreads();               // P(t) visible; dbuf covers WAR

    // ---- kc2,3 v-frags (consumed after 8 MFMAs) ----
    bf16x8 vfB[2];
    #pragma unroll
    for (int kc = 0; kc < 2; ++kc)
      vfB[kc] = *(const bf16x8*)(vp + n0 + 64 + kc*32);

    // ---- PV: acc[ms] += v[cb..cb+16][n-chunk] @ P[n-chunk][m] ----
    #pragma unroll
    for (int kc = 0; kc < 4; ++kc)
      #pragma unroll
      for (int ms = 0; ms < 4; ++ms) {
        const int m = lm + 16*ms;
        bf16x8 pf = *(const bf16x8*)(pbuf + m*256
                                     + ((kc*64 + g*16) ^ swz(m)));
        acc[ms] = __builtin_amdgcn_mfma_f32_16x16x32_bf16(
                    (kc < 2) ? vfA[kc] : vfB[kc-2], pf, acc[ms], 0, 0, 0);
      }
  }

  // ---- denominators: reduce colsum over lane-groups then 8 waves ----
  #pragma unroll
  for (int ms = 0; ms < 4; ++ms) {
    colsum[ms] += __shfl_xor(colsum[ms], 16, 64);
    colsum[ms] += __shfl_xor(colsum[ms], 32, 64);
  }
  if (lane < 16) {
    #pragma unroll
    for (int ms = 0; ms < 4; ++ms) red[w][lm + 16*ms] = colsum[ms];
  }
  __syncthreads();
  if (tid < 64) {
    float sden = 0.f;
    #pragma unroll
    for (int r2 = 0; r2 < 8; ++r2) sden += red[r2][tid];
    dsh[tid] = sden;
  }
  __syncthreads();

  // ---- epilogue: out = gamma*O/denom + x ----
  const float gam = gamma[0];
  float inv[4];
  #pragma unroll
  for (int ms = 0; ms < 4; ++ms) inv[ms] = gam / dsh[lm + 16*ms];

  #pragma unroll
  for (int ms = 0; ms < 4; ++ms)
    #pragma unroll
    for (int r = 0; r < 4; ++r) {
      const int c = cb + g*4 + r;
      const int m = m0 + 16*ms + lm;
      const size_t idx = ((size_t)b*C_ + c)*N_ + m;
      out[idx] = acc[ms][r] * inv[ms] + x[idx];
    }
}

extern "C" void kernel_launch(void* const* d_in, const int* in_sizes, int n_in,
                              void* d_out, int out_size, void* d_ws, size_t ws_size,
                              hipStream_t stream) {
  const float* x     = (const float*)d_in[0];
  const float* Wq    = (const float*)d_in[1];
  const float* bq    = (const float*)d_in[2];
  const float* Wk    = (const float*)d_in[3];
  const float* bk    = (const float*)d_in[4];
  const float* Wv    = (const float*)d_in[5];
  const float* bv    = (const float*)d_in[6];
  const float* gamma = (const float*)d_in[7];
  float* out = (float*)d_out;
  bf16* ws   = (bf16*)d_ws;

  if (ws_size < WS_BYTES) return;   // ~37.9 MB scratch

  prep_w<<<320, 256, 0, stream>>>(Wq, bq, Wk, bk, Wv, bv, ws);
  prep_x<<<dim3(64, 8, 8), 256, 0, stream>>>(x, ws);
  qkv_mfma<<<dim3(64, 8), 256, 0, stream>>>(ws, ws);
  attn_kernel<<<1024, 512, 0, stream>>>(ws, x, gamma, out);
}

// Round 11
// 174.375 us; speedup vs baseline: 1.1945x; 1.1945x over previous
//
#include <hip/hip_runtime.h>
#include <hip/hip_bf16.h>

#define B_   8
#define C_   256
#define CQ_  32
#define N_   4096
#define OC_  320   // stacked output channels: q 0..31 | k 32..63 | v 64..319

typedef __bf16 bf16;
typedef __attribute__((ext_vector_type(8))) __bf16 bf16x8;
typedef __attribute__((ext_vector_type(4))) __bf16 bf16x4;
typedef __attribute__((ext_vector_type(4))) float f32x4;

#define LOG2E 1.4426950408889634f

// ws layout (bf16 element offsets):
//   qT [B][N][CQ] | kT [B][N][CQ] | vb [B][C][N] | Wb [320][256] | xT [B][N][C]
//   then fp32 bias[320] at byte offset BIAS_BYTE.
#define QT_OFF ((size_t)0)
#define KT_OFF ((size_t)B_*N_*CQ_)
#define VB_OFF ((size_t)2*B_*N_*CQ_)
#define WB_OFF (VB_OFF + (size_t)B_*C_*N_)
#define XT_OFF (WB_OFF + (size_t)OC_*C_)
#define WS_END_BF16 (XT_OFF + (size_t)B_*N_*C_)
#define BIAS_BYTE (WS_END_BF16*2)
#define WS_BYTES (BIAS_BYTE + OC_*4)

// exp2 via builtin (compiler-visible TRANS op; hazards handled).
__device__ inline float exp2_hw(float x) {
  return __builtin_amdgcn_exp2f(x);
}

// ---------------------------------------------------------------------------
// prep_w: stack Wq|Wk|Wv -> bf16 Wb[320][256], biases -> fp32[320].
// ---------------------------------------------------------------------------
__global__ __launch_bounds__(256) void prep_w(
    const float* __restrict__ Wq, const float* __restrict__ bq,
    const float* __restrict__ Wk, const float* __restrict__ bk,
    const float* __restrict__ Wv, const float* __restrict__ bv,
    bf16* __restrict__ ws)
{
  const int idx = blockIdx.x*256 + threadIdx.x;      // 0..81919
  const int o = idx >> 8, c = idx & 255;
  const float v = (o < 32) ? Wq[o*C_ + c]
                : (o < 64) ? Wk[(o-32)*C_ + c]
                           : Wv[(o-64)*C_ + c];
  ws[WB_OFF + idx] = (bf16)v;
  if (idx < OC_) {
    const float bb = (idx < 32) ? bq[idx] : (idx < 64) ? bk[idx-32] : bv[idx-64];
    ((float*)((char*)ws + BIAS_BYTE))[idx] = bb;
  }
}

// ---------------------------------------------------------------------------
// prep_x: x fp32 [B][C][N] -> bf16 xT [B][N][C] (B-frag layout, contiguous c).
// ---------------------------------------------------------------------------
__global__ __launch_bounds__(256) void prep_x(
    const float* __restrict__ x, bf16* __restrict__ ws)
{
  const int b  = blockIdx.z;
  const int n  = blockIdx.x*64 + (threadIdx.x & 63);
  const int c0 = blockIdx.y*32 + (threadIdx.x >> 6)*8;
  const float* xp = x + ((size_t)b*C_ + c0)*N_ + n;
  bf16x8 pk;
  #pragma unroll
  for (int j = 0; j < 8; ++j) pk[j] = (bf16)xp[(size_t)j*N_];
  *(bf16x8*)(ws + XT_OFF + ((size_t)b*N_ + n)*C_ + c0) = pk;
}

// ---------------------------------------------------------------------------
// qkv_mfma: D[o][n] = sum_c Wb[o][c] xT[n][c] + bias[o]. Per block: 320 o x
// 64 n. 4 waves; wave w owns 5 o-tiles. K=256 in 8 MFMA steps, no LDS.
// q outputs pre-scaled by LOG2E so attention uses raw 2^x.
// ---------------------------------------------------------------------------
__global__ __launch_bounds__(256) void qkv_mfma(
    const bf16* __restrict__ wsc, bf16* __restrict__ ws)
{
  const int b   = blockIdx.y;
  const int n0  = blockIdx.x * 64;
  const int tid = threadIdx.x, lane = tid & 63;
  const int w   = __builtin_amdgcn_readfirstlane(tid >> 6);
  const int lm  = lane & 15, g = lane >> 4;
  const int obase = w*80;

  const bf16*  Wb   = wsc + WB_OFF;
  const bf16*  xT   = wsc + XT_OFF + (size_t)b*N_*C_;
  const float* bias = (const float*)((const char*)wsc + BIAS_BYTE);

  f32x4 acc[5][4];
  #pragma unroll
  for (int ot = 0; ot < 5; ++ot)
    #pragma unroll
    for (int nt = 0; nt < 4; ++nt)
      acc[ot][nt] = (f32x4){0.f, 0.f, 0.f, 0.f};

  for (int kk = 0; kk < 8; ++kk) {
    bf16x8 wa[5], xf[4];
    #pragma unroll
    for (int ot = 0; ot < 5; ++ot)
      wa[ot] = *(const bf16x8*)(Wb + (size_t)(obase + ot*16 + lm)*C_ + kk*32 + g*8);
    #pragma unroll
    for (int nt = 0; nt < 4; ++nt)
      xf[nt] = *(const bf16x8*)(xT + (size_t)(n0 + nt*16 + lm)*C_ + kk*32 + g*8);
    #pragma unroll
    for (int ot = 0; ot < 5; ++ot)
      #pragma unroll
      for (int nt = 0; nt < 4; ++nt)
        acc[ot][nt] = __builtin_amdgcn_mfma_f32_16x16x32_bf16(
                        wa[ot], xf[nt], acc[ot][nt], 0, 0, 0);
  }

  float bv4[5][4];
  #pragma unroll
  for (int ot = 0; ot < 5; ++ot)
    #pragma unroll
    for (int r = 0; r < 4; ++r)
      bv4[ot][r] = bias[obase + ot*16 + g*4 + r];

  bf16* qT = ws + QT_OFF + (size_t)b*N_*CQ_;
  bf16* kT = ws + KT_OFF + (size_t)b*N_*CQ_;
  bf16* vb = ws + VB_OFF + (size_t)b*C_*N_;

  #pragma unroll
  for (int ot = 0; ot < 5; ++ot) {
    const int O = obase + ot*16;
    #pragma unroll
    for (int nt = 0; nt < 4; ++nt) {
      const int n = n0 + nt*16 + lm;
      if (O < 32) {
        bf16x4 pk;   // q: fold log2(e) so attn exp is a bare v_exp_f32
        #pragma unroll
        for (int r = 0; r < 4; ++r)
          pk[r] = (bf16)((acc[ot][nt][r] + bv4[ot][r]) * LOG2E);
        *(bf16x4*)(qT + (size_t)n*CQ_ + O + g*4) = pk;
      } else if (O < 64) {
        bf16x4 pk;
        #pragma unroll
        for (int r = 0; r < 4; ++r) pk[r] = (bf16)(acc[ot][nt][r] + bv4[ot][r]);
        *(bf16x4*)(kT + (size_t)n*CQ_ + (O - 32) + g*4) = pk;
      } else {
        #pragma unroll
        for (int r = 0; r < 4; ++r)
          vb[(size_t)(O - 64 + g*4 + r)*N_ + n] = (bf16)(acc[ot][nt][r] + bv4[ot][r]);
      }
    }
  }
}

// ---------------------------------------------------------------------------
// attn_kernel (round-3 structure, measured ~112us): 4 waves / 256 threads,
// 512 blocks (b = bid&7 XCD-affine), n-tile 64, 64 barriered tiles.
// Wave w: QK^T slab rows n0+w*16 (4 MFMAs) -> exp2 (q prescaled by log2e)
// -> bf16 -> XOR-swizzled LDS P [64m][128B] (double-buffered, 1 barrier/tile)
// -> PV over c-range [64w,64w+64): 32 MFMAs, each P-read feeds 4 MFMAs
// (cs=4 reuse). v A-frags loaded at tile top (global->reg, L2-resident).
// ---------------------------------------------------------------------------
__global__ __launch_bounds__(256) void attn_kernel(
    const bf16* __restrict__ ws, const float* __restrict__ x,
    const float* __restrict__ gamma, float* __restrict__ out)
{
  const int bid  = blockIdx.x;
  const int b    = bid & 7;
  const int m0   = (bid >> 3) << 6;
  const int tid  = threadIdx.x;
  const int lane = tid & 63;
  const int w    = __builtin_amdgcn_readfirstlane(tid >> 6);   // 0..3
  const int lm   = lane & 15;
  const int g    = lane >> 4;

  const bf16* qT = ws + QT_OFF + (size_t)b*N_*CQ_;
  const bf16* kT = ws + KT_OFF + (size_t)b*N_*CQ_;
  const bf16* vb = ws + VB_OFF + (size_t)b*C_*N_;

  __shared__ __align__(16) char Pb[2][64*128]; // [buf][m][128B swizzled row]
  __shared__ float red[4][64];
  __shared__ float dsh[64];

  // k B-frags for the block's 64 columns (constant over loop)
  bf16x8 kb[4];
  #pragma unroll
  for (int ms = 0; ms < 4; ++ms)
    kb[ms] = *(const bf16x8*)(kT + (size_t)(m0 + ms*16 + lm)*CQ_ + g*8);

  f32x4 acc[4][4];                 // [c-subtile][m-subtile]
  #pragma unroll
  for (int cs = 0; cs < 4; ++cs)
    #pragma unroll
    for (int ms = 0; ms < 4; ++ms)
      acc[cs][ms] = (f32x4){0.f, 0.f, 0.f, 0.f};
  float colsum[4] = {0.f, 0.f, 0.f, 0.f};

  const int c0  = w*64;
  const int swb = w*32 + g*8;      // P-write byte base within row, pre-XOR
  const f32x4 zero4 = (f32x4){0.f, 0.f, 0.f, 0.f};

  for (int t = 0; t < 64; ++t) {
    const int n0 = t*64;

    // ---- issue v A-frag loads early (hide L2 latency under QKT+exp) ----
    bf16x8 vf[4][2];
    #pragma unroll
    for (int cs = 0; cs < 4; ++cs)
      #pragma unroll
      for (int kc = 0; kc < 2; ++kc)
        vf[cs][kc] = *(const bf16x8*)(vb + (size_t)(c0 + cs*16 + lm)*N_
                                         + n0 + kc*32 + g*8);

    // ---- QK^T: S[n0+w*16+.. 16 rows][64 m] ----
    bf16x8 qf = *(const bf16x8*)(qT + (size_t)(n0 + w*16 + lm)*CQ_ + g*8);
    f32x4 s[4];
    #pragma unroll
    for (int ms = 0; ms < 4; ++ms)
      s[ms] = __builtin_amdgcn_mfma_f32_16x16x32_bf16(qf, kb[ms], zero4, 0, 0, 0);

    // ---- exp2 (q prescaled), column partial sums, pack, swizzled P ----
    char* pbuf = Pb[t & 1];
    #pragma unroll
    for (int ms = 0; ms < 4; ++ms) {
      float p0 = exp2_hw(s[ms][0]);
      float p1 = exp2_hw(s[ms][1]);
      float p2 = exp2_hw(s[ms][2]);
      float p3 = exp2_hw(s[ms][3]);
      colsum[ms] += (p0 + p1) + (p2 + p3);
      bf16x4 pk;
      pk[0] = (bf16)p0; pk[1] = (bf16)p1; pk[2] = (bf16)p2; pk[3] = (bf16)p3;
      const int m = lm + 16*ms;
      *(bf16x4*)(pbuf + m*128 + (swb ^ ((m & 7) << 4))) = pk;
    }
    __syncthreads();               // P(t) visible; dbuf removes WAR barrier

    // ---- PV: acc += v[c][n-chunk] @ P[n-chunk][m] ----
    #pragma unroll
    for (int kc = 0; kc < 2; ++kc)
      #pragma unroll
      for (int ms = 0; ms < 4; ++ms) {
        const int m = lm + 16*ms;
        bf16x8 pf = *(const bf16x8*)(pbuf + m*128
                                     + ((kc*64 + g*16) ^ ((m & 7) << 4)));
        #pragma unroll
        for (int cs = 0; cs < 4; ++cs)
          acc[cs][ms] = __builtin_amdgcn_mfma_f32_16x16x32_bf16(
                          vf[cs][kc], pf, acc[cs][ms], 0, 0, 0);
      }
  }

  // ---- denominators: reduce colsum over lane-groups then waves ----
  #pragma unroll
  for (int ms = 0; ms < 4; ++ms) {
    colsum[ms] += __shfl_xor(colsum[ms], 16, 64);
    colsum[ms] += __shfl_xor(colsum[ms], 32, 64);
  }
  if (lane < 16) {
    #pragma unroll
    for (int ms = 0; ms < 4; ++ms) red[w][lm + 16*ms] = colsum[ms];
  }
  __syncthreads();
  if (tid < 64) dsh[tid] = red[0][tid] + red[1][tid] + red[2][tid] + red[3][tid];
  __syncthreads();

  // ---- epilogue: out = gamma*O/denom + x ----
  const float gam = gamma[0];
  float inv[4];
  #pragma unroll
  for (int ms = 0; ms < 4; ++ms) inv[ms] = gam / dsh[lm + 16*ms];

  #pragma unroll
  for (int cs = 0; cs < 4; ++cs)
    #pragma unroll
    for (int ms = 0; ms < 4; ++ms)
      #pragma unroll
      for (int r = 0; r < 4; ++r) {
        const int c = c0 + cs*16 + g*4 + r;
        const int m = m0 + 16*ms + lm;
        const size_t idx = ((size_t)b*C_ + c)*N_ + m;
        out[idx] = acc[cs][ms][r] * inv[ms] + x[idx];
      }
}

extern "C" void kernel_launch(void* const* d_in, const int* in_sizes, int n_in,
                              void* d_out, int out_size, void* d_ws, size_t ws_size,
                              hipStream_t stream) {
  const float* x     = (const float*)d_in[0];
  const float* Wq    = (const float*)d_in[1];
  const float* bq    = (const float*)d_in[2];
  const float* Wk    = (const float*)d_in[3];
  const float* bk    = (const float*)d_in[4];
  const float* Wv    = (const float*)d_in[5];
  const float* bv    = (const float*)d_in[6];
  const float* gamma = (const float*)d_in[7];
  float* out = (float*)d_out;
  bf16* ws   = (bf16*)d_ws;

  if (ws_size < WS_BYTES) return;   // ~37.9 MB scratch

  prep_w<<<320, 256, 0, stream>>>(Wq, bq, Wk, bk, Wv, bv, ws);
  prep_x<<<dim3(64, 8, 8), 256, 0, stream>>>(x, ws);
  qkv_mfma<<<dim3(64, 8), 256, 0, stream>>>(ws, ws);
  attn_kernel<<<512, 256, 0, stream>>>(ws, x, gamma, out);
}